// Round 2
// baseline (99.506 us; speedup 1.0000x reference)
//
#include <hip/hip_runtime.h>
#include <stdint.h>

// Pow2Quant: round each fp32 to the nearest entry of
// {-1,-.5,...,-0.0078125, 0, 0.0078125,...,1} with argmin-first-index
// tie-breaking (positive midpoints round toward smaller value, negative
// midpoints round toward larger magnitude; |x|==2^-8 -> 0 for positive,
// -2^-7 for negative).
__device__ __forceinline__ float pow2_quant(float x) {
    uint32_t b    = __float_as_uint(x);
    uint32_t sign = b & 0x80000000u;
    uint32_t a    = b & 0x7FFFFFFFu;      // |x| bits (monotone as uint)
    uint32_t mant = a & 0x007FFFFFu;
    int e = (int)(a >> 23) - 127;

    // Round |x| to nearest power of two. Midpoint is mantissa 1.5 (0x400000).
    // positive: strict > (ties go down); negative: >= (ties go up in magnitude).
    bool up = sign ? (mant >= 0x00400000u) : (mant > 0x00400000u);
    int e2 = e + (up ? 1 : 0);

    // Clamp exponent into codebook range [-7, 0].
    int ec = e2 > 0 ? 0 : (e2 < -7 ? -7 : e2);
    uint32_t magbits = (uint32_t)(127 + ec) << 23;

    // Zero region: |x| <= 2^-8 (positive, tie -> 0) / |x| < 2^-8 (negative,
    // tie -> -2^-7). 2^-8 bits = 0x3B800000.
    bool zero = sign ? (a < 0x3B800000u) : (a <= 0x3B800000u);
    uint32_t res = (zero ? 0u : magbits) | sign;
    return __uint_as_float(res);
}

__global__ void __launch_bounds__(256) pow2quant_kernel(const float* __restrict__ in,
                                                        float* __restrict__ out,
                                                        int n) {
    const int n4 = n >> 2;
    const float4* __restrict__ in4  = (const float4*)in;
    float4* __restrict__ out4 = (float4*)out;

    int stride = gridDim.x * blockDim.x;
    for (int i = blockIdx.x * blockDim.x + threadIdx.x; i < n4; i += stride) {
        float4 v = in4[i];
        float4 r;
        r.x = pow2_quant(v.x);
        r.y = pow2_quant(v.y);
        r.z = pow2_quant(v.z);
        r.w = pow2_quant(v.w);
        out4[i] = r;
    }

    // Scalar tail (n % 4), handled by the first few threads of the grid.
    // (n = 16*256*56*56 is divisible by 4, so this is normally dead.)
    int tail_start = n4 << 2;
    int ti = blockIdx.x * blockDim.x + threadIdx.x;
    if (ti < n - tail_start) {
        out[tail_start + ti] = pow2_quant(in[tail_start + ti]);
    }
}

extern "C" void kernel_launch(void* const* d_in, const int* in_sizes, int n_in,
                              void* d_out, int out_size, void* d_ws, size_t ws_size,
                              hipStream_t stream) {
    const float* x = (const float*)d_in[0];
    // d_in[1] is the codebook; its values are compile-time constants of the
    // reference, folded into pow2_quant.
    float* out = (float*)d_out;
    int n = in_sizes[0];

    int n4 = n >> 2;
    int blocks = (n4 + 255) / 256;
    if (blocks > 2048) blocks = 2048;   // grid-stride the rest (G11)
    if (blocks < 1) blocks = 1;
    pow2quant_kernel<<<blocks, 256, 0, stream>>>(x, out, n);
}